// Round 1
// baseline (50.411 us; speedup 1.0000x reference)
//
#include <hip/hip_runtime.h>

#define KERNEL_LEN 128
#define INPUT_LEN 1000000
#define PATH_NUM 10
#define L_TOTAL (INPUT_LEN + KERNEL_LEN)
#define BLOCKS_PER_PATH 128
#define BLOCK_SIZE 256

__global__ __launch_bounds__(BLOCK_SIZE) void dtw_spring_npath_kernel(
    const float* __restrict__ kern,
    const float* __restrict__ x,
    const int*   __restrict__ path_k,
    const int*   __restrict__ path_i,
    const int*   __restrict__ path_length,
    const int*   __restrict__ path_num,
    float*       __restrict__ out)
{
    __shared__ float k_lds[KERNEL_LEN];
    const int tid = threadIdx.x;
    if (tid < KERNEL_LEN) k_lds[tid] = kern[tid];
    __syncthreads();

    const int p = blockIdx.y;
    const int n = min(path_num[0], PATH_NUM);
    if (p >= n) return;                 // block-uniform exit; out already zeroed

    const int len  = path_length[p];
    const int len4 = len & ~3;

    const int* __restrict__ pk = path_k + (size_t)p * L_TOTAL;
    const int* __restrict__ pi = path_i + (size_t)p * L_TOTAL;

    float acc = 0.0f;
    const int stride = gridDim.x * BLOCK_SIZE * 4;
    for (int t = (blockIdx.x * BLOCK_SIZE + tid) * 4; t < len4; t += stride) {
        // L=1000128 divisible by 4 and rows 16B-aligned -> int4 loads are safe
        const int4 vk = *reinterpret_cast<const int4*>(pk + t);
        const int4 vi = *reinterpret_cast<const int4*>(pi + t);
        float d0 = k_lds[vk.x] - x[vi.x];
        float d1 = k_lds[vk.y] - x[vi.y];
        float d2 = k_lds[vk.z] - x[vi.z];
        float d3 = k_lds[vk.w] - x[vi.w];
        acc += d0 * d0 + d1 * d1 + d2 * d2 + d3 * d3;
    }
    // tail (< 4 elements), handled by block x==0 only
    if (blockIdx.x == 0 && tid < (len - len4)) {
        const int t = len4 + tid;
        const float d = k_lds[pk[t]] - x[pi[t]];
        acc += d * d;
    }

    // wave (64-lane) reduction
    #pragma unroll
    for (int off = 32; off > 0; off >>= 1)
        acc += __shfl_down(acc, off, 64);

    __shared__ float wsum[BLOCK_SIZE / 64];
    const int wave = tid >> 6;
    if ((tid & 63) == 0) wsum[wave] = acc;
    __syncthreads();
    if (tid == 0) {
        float s = 0.0f;
        #pragma unroll
        for (int w = 0; w < BLOCK_SIZE / 64; ++w) s += wsum[w];
        atomicAdd(&out[p], s);
    }
}

extern "C" void kernel_launch(void* const* d_in, const int* in_sizes, int n_in,
                              void* d_out, int out_size, void* d_ws, size_t ws_size,
                              hipStream_t stream) {
    const float* kern        = (const float*)d_in[0];
    const float* x           = (const float*)d_in[1];
    const int*   path_k      = (const int*)d_in[2];
    const int*   path_i      = (const int*)d_in[3];
    const int*   path_length = (const int*)d_in[4];
    const int*   path_num    = (const int*)d_in[5];
    float*       out         = (float*)d_out;

    hipMemsetAsync(out, 0, (size_t)out_size * sizeof(float), stream);

    dim3 grid(BLOCKS_PER_PATH, PATH_NUM);
    dim3 block(BLOCK_SIZE);
    dtw_spring_npath_kernel<<<grid, block, 0, stream>>>(
        kern, x, path_k, path_i, path_length, path_num, out);
}